// Round 8
// baseline (184.306 us; speedup 1.0000x reference)
//
#include <hip/hip_runtime.h>
#include <hip/hip_bf16.h>

#define B_    8
#define DIM_  256
#define NH_   8
#define HD_   32
#define KD_   16
#define HOUT_ 512
#define N_    1024
#define SCALE_ 0.25f
#define EPS_  1e-3f

#if __has_builtin(__builtin_amdgcn_mfma_f32_16x16x16bf16_1k)
#define USE_1K 1
#else
#define USE_1K 0
#endif

typedef unsigned short u16;
typedef __attribute__((ext_vector_type(8))) short short8;   // 8 bf16 (4 VGPR)
typedef __attribute__((ext_vector_type(4))) short short4b;  // 4 bf16 (2 VGPR)
typedef __attribute__((ext_vector_type(4))) float f32x4;

union H4 { uint2 u; u16 e[4]; };

__device__ __forceinline__ float b2f(u16 u) {
    union { unsigned int i; float f; } c;
    c.i = ((unsigned int)u) << 16;
    return c.f;
}

__device__ __forceinline__ u16 f2b(float f) {
    union { float f; unsigned int i; } c;
    c.f = f;
    unsigned int x = c.i;
    return (u16)((x + 0x7fffu + ((x >> 16) & 1u)) >> 16);  // RNE
}

// ============ Kernel 0: prep — weights->bf16, fold all BN ============
__global__ __launch_bounds__(256) void k_prep(
    const float* __restrict__ qw, const float* __restrict__ pw,
    const float* __restrict__ pew,
    const float* __restrict__ qg, const float* __restrict__ qb,
    const float* __restrict__ qm, const float* __restrict__ qv,
    const float* __restrict__ pg, const float* __restrict__ pb,
    const float* __restrict__ pm, const float* __restrict__ pv,
    const float* __restrict__ eg, const float* __restrict__ eb,
    const float* __restrict__ em, const float* __restrict__ ev,
    u16* __restrict__ wq_bf, u16* __restrict__ wp_bf,
    float2* __restrict__ bnq, float2* __restrict__ bnp,
    float* __restrict__ wpe, float* __restrict__ bnpe)
{
    int i = blockIdx.x * 256 + threadIdx.x;          // 0 .. 131071
    wq_bf[i] = f2b(qw[i]);
    if (i < 65536) wp_bf[i] = f2b(pw[i]);
    if (i < 512) {
        float inv = qg[i] / sqrtf(qv[i] + EPS_);
        bnq[i] = make_float2(inv, qb[i] - qm[i] * inv);
    } else if (i < 768) {
        int o = i - 512;
        float inv = pg[o] / sqrtf(pv[o] + EPS_);
        bnp[o] = make_float2(inv, pb[o] - pm[o] * inv);
    }
    if (i < 2304) {                    // pe: fold inv into the 9 taps
        int c = i / 9;
        float inv = eg[c] / sqrtf(ev[c] + EPS_);
        wpe[i] = pew[i] * inv;
        if (i % 9 == 0) bnpe[c] = eb[c] - em[c] * inv;
    }
}

// ============ Kernel 0b: xT[b][n][c] bf16 <- x[b][c][n] fp32 ============
__global__ __launch_bounds__(256) void k_xt(
    const float* __restrict__ x, u16* __restrict__ xT)
{
    __shared__ float t_s[64][65];
    int blk = blockIdx.x;
    int nt = blk & 15, ct = (blk >> 4) & 3, b = blk >> 6;
    int t = threadIdx.x;
    int c0 = ct * 64, n0 = nt * 64;
    #pragma unroll
    for (int i = 0; i < 16; ++i) {
        int idx = i * 256 + t;
        int c = idx >> 6, n = idx & 63;
        t_s[n][c] = x[(size_t)(b * DIM_ + c0 + c) * N_ + n0 + n];
    }
    __syncthreads();
    #pragma unroll
    for (int i = 0; i < 16; ++i) {
        int idx = i * 256 + t;
        int n = idx >> 6, c = idx & 63;
        xT[(size_t)(b * N_ + n0 + n) * DIM_ + c0 + c] = f2b(t_s[n][c]);
    }
}

// ============ Kernel 1: qkv = BN(qkv_w @ x) -> bf16 [o][n], MFMA ============
__global__ __launch_bounds__(256) void k_qkv(
    const u16* __restrict__ xT, const u16* __restrict__ wbf,
    const float2* __restrict__ bn, u16* __restrict__ qkv)
{
    int blk = blockIdx.x;
    int nb = blk & 7, ob = (blk >> 3) & 7, b = blk >> 6;
    int t = threadIdx.x;
    int wv_ = t >> 6, lane = t & 63, quad = lane >> 4, l16 = lane & 15;
    int o_base = ob * 64 + (wv_ & 1) * 32;
    int n_base = nb * 128 + (wv_ >> 1) * 64;

    f32x4 acc[2][4];
    #pragma unroll
    for (int ot = 0; ot < 2; ++ot)
        #pragma unroll
        for (int nt = 0; nt < 4; ++nt) acc[ot][nt] = (f32x4){0.f, 0.f, 0.f, 0.f};

    const u16* xb = xT + (size_t)b * N_ * DIM_;
    for (int c0 = 0; c0 < DIM_; c0 += 32) {
        short8 af[2];
        #pragma unroll
        for (int ot = 0; ot < 2; ++ot)
            af[ot] = *(const short8*)(wbf + (size_t)(o_base + ot * 16 + l16) * DIM_ + c0 + quad * 8);
        short8 bf[4];
        #pragma unroll
        for (int nt = 0; nt < 4; ++nt)
            bf[nt] = *(const short8*)(xb + (size_t)(n_base + nt * 16 + l16) * DIM_ + c0 + quad * 8);
        #pragma unroll
        for (int ot = 0; ot < 2; ++ot)
            #pragma unroll
            for (int nt = 0; nt < 4; ++nt)
                acc[ot][nt] = __builtin_amdgcn_mfma_f32_16x16x32_bf16(af[ot], bf[nt], acc[ot][nt], 0, 0, 0);
    }
    #pragma unroll
    for (int ot = 0; ot < 2; ++ot)
        #pragma unroll
        for (int r = 0; r < 4; ++r) {
            int o = o_base + ot * 16 + quad * 4 + r;
            float2 ib = bn[o];
            u16* dst = qkv + (size_t)(b * HOUT_ + o) * N_ + n_base + l16;
            #pragma unroll
            for (int nt = 0; nt < 4; ++nt)
                dst[nt * 16] = f2b(acc[ot][nt][r] * ib.x + ib.y);
        }
}

// ============ Kernel 2: MFMA flash attention + fused pe, P in registers ============
// S^T = mfma(K-frag, Q-frag): C gives col=q, rows=key quad*4+r == the B-operand
// layout of the K=16 PV MFMA, so P never touches LDS. O arrives transposed
// [d][q], matching the o_s epilogue. Fallback (no 1k builtin): R7 p_s path.
#if USE_1K
struct MainSmem { u16 k_t[256][24]; };
#else
struct MainSmem { u16 k_t[256][24]; u16 p_s[4][16][80]; };
#endif
union  SmemU    { MainSmem m; float v_pe[128][33]; };

__global__ __launch_bounds__(256) void k_attn(
    const u16* __restrict__ qkv, const float* __restrict__ wpe,
    const float* __restrict__ bnpe, u16* __restrict__ xattnT)
{
    __shared__ SmemU su;
    __shared__ u16   q_t[64][24];
    __shared__ float o_s[4][32][17];

    int blk = blockIdx.x;
    int qb = blk & 15;
    int h  = (blk >> 4) & 7;
    int b  = blk >> 7;
    int t    = threadIdx.x;
    int wv_  = t >> 6;
    int lane = t & 63;
    int quad = lane >> 4;
    int l16  = lane & 15;
    const u16* base = qkv + (size_t)(b * HOUT_ + h * 64) * N_;  // q:d, k:16+d, v:32+d

    {   // stage q transposed+scaled (lane = q, conflict-free)
        int q = t & 63, d4 = (t >> 6) * 4;
        H4 hh;
        #pragma unroll
        for (int i = 0; i < 4; ++i)
            hh.e[i] = f2b(b2f(base[(size_t)(d4 + i) * N_ + qb * 64 + q]) * SCALE_);
        *(uint2*)&q_t[q][d4] = hh.u;
    }
    __syncthreads();

    short8 qf = {0, 0, 0, 0, 0, 0, 0, 0};
    if (quad < 2) qf = *(const short8*)&q_t[wv_ * 16 + l16][quad * 8];

#if USE_1K
    f32x4 oaT0 = {0.f, 0.f, 0.f, 0.f};
    f32x4 oaT1 = {0.f, 0.f, 0.f, 0.f};
    float l_part = 0.f;

    for (int ch = 0; ch < 4; ++ch) {
        int ch0 = ch * 256;
        __syncthreads();
        {   // stage 256 keys (lane = key, conflict-free)
            #pragma unroll
            for (int d4 = 0; d4 < 16; d4 += 4) {
                H4 hh;
                #pragma unroll
                for (int i = 0; i < 4; ++i)
                    hh.e[i] = base[(size_t)(16 + d4 + i) * N_ + ch0 + t];
                *(uint2*)&su.m.k_t[t][d4] = hh.u;
            }
        }
        __syncthreads();

        #pragma unroll 4
        for (int kt = 0; kt < 16; ++kt) {       // 16-key tiles
            int key0 = ch0 + kt * 16;
            short8 kf = {0, 0, 0, 0, 0, 0, 0, 0};
            if (quad < 2) kf = *(const short8*)&su.m.k_t[kt * 16 + l16][quad * 8];
            f32x4 zero = {0.f, 0.f, 0.f, 0.f};
            f32x4 sT = __builtin_amdgcn_mfma_f32_16x16x32_bf16(kf, qf, zero, 0, 0, 0);
            short4b pb;
            #pragma unroll
            for (int r = 0; r < 4; ++r) {
                float p = __expf(fminf(sT[r], 80.f));
                l_part += p;
                pb[r] = f2b(p);
            }
            short4b vf0 = *(const short4b*)(base + (size_t)(32 + l16) * N_ + key0 + quad * 4);
            oaT0 = __builtin_amdgcn_mfma_f32_16x16x16bf16_1k(vf0, pb, oaT0, 0, 0, 0);
            short4b vf1 = *(const short4b*)(base + (size_t)(48 + l16) * N_ + key0 + quad * 4);
            oaT1 = __builtin_amdgcn_mfma_f32_16x16x16bf16_1k(vf1, pb, oaT1, 0, 0, 0);
        }
    }

    // l: sum across the 4 quads (lanes differing in bits 4,5)
    l_part += __shfl_xor(l_part, 16);
    l_part += __shfl_xor(l_part, 32);
    float linv = 1.f / fmaxf(l_part, 1e-30f);
    // O^T is already [d][q]: write straight into o_s
    #pragma unroll
    for (int r = 0; r < 4; ++r) {
        o_s[wv_][quad * 4 + r][l16]      = oaT0[r] * linv;
        o_s[wv_][16 + quad * 4 + r][l16] = oaT1[r] * linv;
    }
#else
    f32x4 oa0 = {0.f, 0.f, 0.f, 0.f};
    f32x4 oa1 = {0.f, 0.f, 0.f, 0.f};
    float l_acc[4] = {0.f, 0.f, 0.f, 0.f};

    for (int ch = 0; ch < 4; ++ch) {
        int ch0 = ch * 256;
        __syncthreads();
        {
            #pragma unroll
            for (int d4 = 0; d4 < 16; d4 += 4) {
                H4 hh;
                #pragma unroll
                for (int i = 0; i < 4; ++i)
                    hh.e[i] = base[(size_t)(16 + d4 + i) * N_ + ch0 + t];
                *(uint2*)&su.m.k_t[t][d4] = hh.u;
            }
        }
        __syncthreads();

        for (int kt = 0; kt < 4; ++kt) {
            int key0 = ch0 + kt * 64;
            #pragma unroll
            for (int nt = 0; nt < 4; ++nt) {
                short8 kf = {0, 0, 0, 0, 0, 0, 0, 0};
                if (quad < 2) kf = *(const short8*)&su.m.k_t[kt * 64 + nt * 16 + l16][quad * 8];
                f32x4 zero = {0.f, 0.f, 0.f, 0.f};
                f32x4 s = __builtin_amdgcn_mfma_f32_16x16x32_bf16(qf, kf, zero, 0, 0, 0);
                #pragma unroll
                for (int r = 0; r < 4; ++r) {
                    float p = __expf(fminf(s[r], 80.f));
                    l_acc[r] += p;
                    su.m.p_s[wv_][quad * 4 + r][nt * 16 + l16] = f2b(p);
                }
            }
            #pragma unroll
            for (int kc = 0; kc < 2; ++kc) {
                short8 pf = *(const short8*)&su.m.p_s[wv_][l16][kc * 32 + quad * 8];
                {
                    const u16* vsrc = base + (size_t)(32 + l16) * N_ + key0 + kc * 32 + quad * 8;
                    oa0 = __builtin_amdgcn_mfma_f32_16x16x32_bf16(pf, *(const short8*)vsrc, oa0, 0, 0, 0);
                }
                {
                    const u16* vsrc = base + (size_t)(48 + l16) * N_ + key0 + kc * 32 + quad * 8;
                    oa1 = __builtin_amdgcn_mfma_f32_16x16x32_bf16(pf, *(const short8*)vsrc, oa1, 0, 0, 0);
                }
            }
        }
    }
    #pragma unroll
    for (int r = 0; r < 4; ++r) {
        float v = l_acc[r];
        v += __shfl_xor(v, 1);
        v += __shfl_xor(v, 2);
        v += __shfl_xor(v, 4);
        v += __shfl_xor(v, 8);
        l_acc[r] = v;
    }
    #pragma unroll
    for (int r = 0; r < 4; ++r) {
        o_s[wv_][l16][quad * 4 + r]      = oa0[r] / l_acc[r];
        o_s[wv_][16 + l16][quad * 4 + r] = oa1[r] / l_acc[r];
    }
#endif
    __syncthreads();   // all waves done with k_t (+p_s) + o_s complete

    {   // stage v patch: rows 2qb-1 .. 2qb+2, 32 d channels, zeros off-image
        int ybase = qb * 2 - 1;
        #pragma unroll
        for (int i = 0; i < 16; ++i) {
            int idx = i * 256 + t;
            int d = idx >> 7, px = idx & 127;
            int y = ybase + (px >> 5);
            float v = 0.f;
            if (y >= 0 && y < 32)
                v = b2f(base[(size_t)(32 + d) * N_ + y * 32 + (px & 31)]);
            su.v_pe[px][d] = v;
        }
    }
    __syncthreads();

    {   // pe compute + add + transposed bf16 store
        int d = t & 31, pxg = t >> 5;        // 8 pixel-groups of 8
        int c = h * 32 + d;
        float w9[9];
        #pragma unroll
        for (int k = 0; k < 9; ++k) w9[k] = wpe[c * 9 + k];
        float beta = bnpe[c];
        #pragma unroll
        for (int ii = 0; ii < 8; ++ii) {
            int pl = pxg * 8 + ii;           // 0..63 local pixel
            int xx0 = pl & 31;
            float s = beta;
            #pragma unroll
            for (int dy = -1; dy <= 1; ++dy) {
                #pragma unroll
                for (int dx = -1; dx <= 1; ++dx) {
                    int xx = xx0 + dx;
                    if (xx < 0 || xx > 31) continue;
                    s += w9[(dy + 1) * 3 + (dx + 1)] * su.v_pe[pl + 32 + dy * 32 + dx][d];
                }
            }
            float o = o_s[pl >> 4][d][pl & 15];
            xattnT[(size_t)(b * N_ + qb * 64 + pl) * DIM_ + c] = f2b(o + s);
        }
    }
}

// ============ Kernel 4: out = BN(proj_w @ xattn) fp32, MFMA ============
__global__ __launch_bounds__(256) void k_proj(
    const u16* __restrict__ xattnT, const u16* __restrict__ wbf,
    const float2* __restrict__ bn, float* __restrict__ out)
{
    int blk = blockIdx.x;
    int nb = blk & 7, ob = (blk >> 3) & 3, b = blk >> 5;
    int t = threadIdx.x;
    int wv_ = t >> 6, lane = t & 63, quad = lane >> 4, l16 = lane & 15;
    int o_base = ob * 64 + (wv_ & 1) * 32;
    int n_base = nb * 128 + (wv_ >> 1) * 64;

    f32x4 acc[2][4];
    #pragma unroll
    for (int ot = 0; ot < 2; ++ot)
        #pragma unroll
        for (int nt = 0; nt < 4; ++nt) acc[ot][nt] = (f32x4){0.f, 0.f, 0.f, 0.f};

    const u16* xb = xattnT + (size_t)b * N_ * DIM_;
    for (int c0 = 0; c0 < DIM_; c0 += 32) {
        short8 af[2];
        #pragma unroll
        for (int ot = 0; ot < 2; ++ot)
            af[ot] = *(const short8*)(wbf + (size_t)(o_base + ot * 16 + l16) * DIM_ + c0 + quad * 8);
        short8 bf[4];
        #pragma unroll
        for (int nt = 0; nt < 4; ++nt)
            bf[nt] = *(const short8*)(xb + (size_t)(n_base + nt * 16 + l16) * DIM_ + c0 + quad * 8);
        #pragma unroll
        for (int ot = 0; ot < 2; ++ot)
            #pragma unroll
            for (int nt = 0; nt < 4; ++nt)
                acc[ot][nt] = __builtin_amdgcn_mfma_f32_16x16x32_bf16(af[ot], bf[nt], acc[ot][nt], 0, 0, 0);
    }
    #pragma unroll
    for (int ot = 0; ot < 2; ++ot)
        #pragma unroll
        for (int r = 0; r < 4; ++r) {
            int o = o_base + ot * 16 + quad * 4 + r;
            float2 ib = bn[o];
            float* dst = out + (size_t)(b * DIM_ + o) * N_ + n_base + l16;
            #pragma unroll
            for (int nt = 0; nt < 4; ++nt)
                dst[nt * 16] = acc[ot][nt][r] * ib.x + ib.y;
        }
}

extern "C" void kernel_launch(void* const* d_in, const int* in_sizes, int n_in,
                              void* d_out, int out_size, void* d_ws, size_t ws_size,
                              hipStream_t stream)
{
    const float* x      = (const float*)d_in[0];
    const float* qkv_w  = (const float*)d_in[1];
    const float* qkv_g  = (const float*)d_in[2];
    const float* qkv_b  = (const float*)d_in[3];
    const float* qkv_m  = (const float*)d_in[4];
    const float* qkv_v  = (const float*)d_in[5];
    const float* pe_w   = (const float*)d_in[6];
    const float* pe_g   = (const float*)d_in[7];
    const float* pe_b   = (const float*)d_in[8];
    const float* pe_m   = (const float*)d_in[9];
    const float* pe_v   = (const float*)d_in[10];
    const float* proj_w = (const float*)d_in[11];
    const float* proj_g = (const float*)d_in[12];
    const float* proj_b = (const float*)d_in[13];
    const float* proj_m = (const float*)d_in[14];
    const float* proj_v = (const float*)d_in[15];
    float* out = (float*)d_out;

    // ws layout
    char* p = (char*)d_ws;
    u16*    qkv    = (u16*)p;    p += (size_t)B_ * HOUT_ * N_ * sizeof(u16);   // 8 MB
    u16*    xT     = (u16*)p;    p += (size_t)B_ * N_ * DIM_ * sizeof(u16);    // 4 MB
    u16*    xattnT = (u16*)p;    p += (size_t)B_ * N_ * DIM_ * sizeof(u16);    // 4 MB
    u16*    wq_bf  = (u16*)p;    p += (size_t)HOUT_ * DIM_ * sizeof(u16);      // 256 KB
    u16*    wp_bf  = (u16*)p;    p += (size_t)DIM_ * DIM_ * sizeof(u16);       // 128 KB
    float2* bnq    = (float2*)p; p += 512 * sizeof(float2);
    float2* bnp    = (float2*)p; p += 256 * sizeof(float2);
    float*  wpe    = (float*)p;  p += 2304 * sizeof(float);
    float*  bnpe   = (float*)p;

    hipLaunchKernelGGL(k_prep, dim3(512), dim3(256), 0, stream,
                       qkv_w, proj_w, pe_w,
                       qkv_g, qkv_b, qkv_m, qkv_v,
                       proj_g, proj_b, proj_m, proj_v,
                       pe_g, pe_b, pe_m, pe_v,
                       wq_bf, wp_bf, bnq, bnp, wpe, bnpe);
    hipLaunchKernelGGL(k_xt, dim3(512), dim3(256), 0, stream, x, xT);
    hipLaunchKernelGGL(k_qkv, dim3(512), dim3(256), 0, stream,
                       xT, wq_bf, bnq, qkv);
    hipLaunchKernelGGL(k_attn, dim3(B_ * NH_ * 16), dim3(256), 0, stream,
                       qkv, wpe, bnpe, xattnT);
    hipLaunchKernelGGL(k_proj, dim3(256), dim3(256), 0, stream,
                       xattnT, wp_bf, bnp, out);
}

// Round 9
// 153.025 us; speedup vs baseline: 1.2044x; 1.2044x over previous
//
#include <hip/hip_runtime.h>
#include <hip/hip_bf16.h>

#define B_    8
#define DIM_  256
#define NH_   8
#define HD_   32
#define KD_   16
#define HOUT_ 512
#define N_    1024
#define SCALE_ 0.25f
#define EPS_  1e-3f

typedef unsigned short u16;
typedef __attribute__((ext_vector_type(8))) short short8;   // 8 bf16 (4 VGPR)
typedef __attribute__((ext_vector_type(4))) short short4b;  // 4 bf16 (2 VGPR)
typedef __attribute__((ext_vector_type(4))) float f32x4;

union H4 { uint2 u; u16 e[4]; };

__device__ __forceinline__ float b2f(u16 u) {
    union { unsigned int i; float f; } c;
    c.i = ((unsigned int)u) << 16;
    return c.f;
}

__device__ __forceinline__ u16 f2b(float f) {
    union { float f; unsigned int i; } c;
    c.f = f;
    unsigned int x = c.i;
    return (u16)((x + 0x7fffu + ((x >> 16) & 1u)) >> 16);  // RNE
}

// ============ Kernel 0: fused prep (weights->bf16, fold BN) + x transpose ============
// blocks 0..511: xT tile transpose; blocks 512..1023: weight prep.
__global__ __launch_bounds__(256) void k_pre(
    const float* __restrict__ x, u16* __restrict__ xT,
    const float* __restrict__ qw, const float* __restrict__ pw,
    const float* __restrict__ pew,
    const float* __restrict__ qg, const float* __restrict__ qb,
    const float* __restrict__ qm, const float* __restrict__ qv,
    const float* __restrict__ pg, const float* __restrict__ pb,
    const float* __restrict__ pm, const float* __restrict__ pv,
    const float* __restrict__ eg, const float* __restrict__ eb,
    const float* __restrict__ em, const float* __restrict__ ev,
    u16* __restrict__ wq_bf, u16* __restrict__ wp_bf,
    float2* __restrict__ bnq, float2* __restrict__ bnp,
    float* __restrict__ wpe, float* __restrict__ bnpe)
{
    __shared__ float t_s[64][65];
    int blk = blockIdx.x;
    int t = threadIdx.x;
    if (blk >= 512) {
        int i = (blk - 512) * 256 + t;          // 0 .. 131071
        wq_bf[i] = f2b(qw[i]);
        if (i < 65536) wp_bf[i] = f2b(pw[i]);
        if (i < 512) {
            float inv = qg[i] / sqrtf(qv[i] + EPS_);
            bnq[i] = make_float2(inv, qb[i] - qm[i] * inv);
        } else if (i < 768) {
            int o = i - 512;
            float inv = pg[o] / sqrtf(pv[o] + EPS_);
            bnp[o] = make_float2(inv, pb[o] - pm[o] * inv);
        }
        if (i < 2304) {
            int c = i / 9;
            float inv = eg[c] / sqrtf(ev[c] + EPS_);
            wpe[i] = pew[i] * inv;
            if (i % 9 == 0) bnpe[c] = eb[c] - em[c] * inv;
        }
        return;
    }
    int nt = blk & 15, ct = (blk >> 4) & 3, b = blk >> 6;
    int c0 = ct * 64, n0 = nt * 64;
    #pragma unroll
    for (int i = 0; i < 16; ++i) {
        int idx = i * 256 + t;
        int c = idx >> 6, n = idx & 63;
        t_s[n][c] = x[(size_t)(b * DIM_ + c0 + c) * N_ + n0 + n];
    }
    __syncthreads();
    #pragma unroll
    for (int i = 0; i < 16; ++i) {
        int idx = i * 256 + t;
        int n = idx >> 6, c = idx & 63;
        xT[(size_t)(b * N_ + n0 + n) * DIM_ + c0 + c] = f2b(t_s[n][c]);
    }
}

// ============ Kernel 1: qkv = BN(qkv_w @ x) -> bf16 [o][n], MFMA ============
__global__ __launch_bounds__(256) void k_qkv(
    const u16* __restrict__ xT, const u16* __restrict__ wbf,
    const float2* __restrict__ bn, u16* __restrict__ qkv)
{
    int blk = blockIdx.x;
    int nb = blk & 7, ob = (blk >> 3) & 7, b = blk >> 6;
    int t = threadIdx.x;
    int wv_ = t >> 6, lane = t & 63, quad = lane >> 4, l16 = lane & 15;
    int o_base = ob * 64 + (wv_ & 1) * 32;
    int n_base = nb * 128 + (wv_ >> 1) * 64;

    f32x4 acc[2][4];
    #pragma unroll
    for (int ot = 0; ot < 2; ++ot)
        #pragma unroll
        for (int nt = 0; nt < 4; ++nt) acc[ot][nt] = (f32x4){0.f, 0.f, 0.f, 0.f};

    const u16* xb = xT + (size_t)b * N_ * DIM_;
    for (int c0 = 0; c0 < DIM_; c0 += 32) {
        short8 af[2];
        #pragma unroll
        for (int ot = 0; ot < 2; ++ot)
            af[ot] = *(const short8*)(wbf + (size_t)(o_base + ot * 16 + l16) * DIM_ + c0 + quad * 8);
        short8 bf[4];
        #pragma unroll
        for (int nt = 0; nt < 4; ++nt)
            bf[nt] = *(const short8*)(xb + (size_t)(n_base + nt * 16 + l16) * DIM_ + c0 + quad * 8);
        #pragma unroll
        for (int ot = 0; ot < 2; ++ot)
            #pragma unroll
            for (int nt = 0; nt < 4; ++nt)
                acc[ot][nt] = __builtin_amdgcn_mfma_f32_16x16x32_bf16(af[ot], bf[nt], acc[ot][nt], 0, 0, 0);
    }
    #pragma unroll
    for (int ot = 0; ot < 2; ++ot)
        #pragma unroll
        for (int r = 0; r < 4; ++r) {
            int o = o_base + ot * 16 + quad * 4 + r;
            float2 ib = bn[o];
            u16* dst = qkv + (size_t)(b * HOUT_ + o) * N_ + n_base + l16;
            #pragma unroll
            for (int nt = 0; nt < 4; ++nt)
                dst[nt * 16] = f2b(acc[ot][nt][r] * ib.x + ib.y);
        }
}

// ============ Kernel 2: MFMA flash attention, register-P, 2 q-tiles/wave ============
// S^T = mfma_32(K,Q) -> C cols=q, rows=keys(quad*4+r) == B-operand layout of the
// 16x16x16_1k PV MFMA (verified R8). Each wave owns 32 q (2 tiles): per 16-key
// tile 2 independent QK chains + 4 PV chains; V frags shared across q-tiles.
// Block = 128 q = 4 image rows; fused depthwise-3x3 pe in the epilogue.
// grid = 8qc x 8h x 8b = 512, 4 waves.
struct MainS { u16 q_t[128][24]; u16 k_t[256][24]; };
union  SmemU { MainS m; float v_pe[192][33]; };

__global__ __launch_bounds__(256) void k_attn(
    const u16* __restrict__ qkv, const float* __restrict__ wpe,
    const float* __restrict__ bnpe, u16* __restrict__ xattnT)
{
    __shared__ SmemU su;
    __shared__ u16 o_s[4][32][34];   // [wave][d][q] bf16

    int blk = blockIdx.x;
    int qc = blk & 7;
    int h  = (blk >> 3) & 7;
    int b  = blk >> 6;
    int t    = threadIdx.x;
    int wv_  = t >> 6;
    int lane = t & 63;
    int quad = lane >> 4;
    int l16  = lane & 15;
    const u16* base = qkv + (size_t)(b * HOUT_ + h * 64) * N_;  // q:d, k:16+d, v:32+d
    int q0g = qc * 128;

    {   // stage 128 q transposed+scaled (lane = q, conflict-free)
        int q = t & 127, dh = (t >> 7) * 8;
        H4 a, c4;
        #pragma unroll
        for (int i = 0; i < 4; ++i)
            a.e[i]  = f2b(b2f(base[(size_t)(dh + i) * N_ + q0g + q]) * SCALE_);
        #pragma unroll
        for (int i = 0; i < 4; ++i)
            c4.e[i] = f2b(b2f(base[(size_t)(dh + 4 + i) * N_ + q0g + q]) * SCALE_);
        *(uint2*)&su.m.q_t[q][dh]     = a.u;
        *(uint2*)&su.m.q_t[q][dh + 4] = c4.u;
    }
    __syncthreads();

    short8 qf[2];
    #pragma unroll
    for (int qt = 0; qt < 2; ++qt) {
        qf[qt] = (short8){0, 0, 0, 0, 0, 0, 0, 0};
        if (quad < 2)
            qf[qt] = *(const short8*)&su.m.q_t[wv_ * 32 + qt * 16 + l16][quad * 8];
    }

    f32x4 oa[2][2];
    #pragma unroll
    for (int qt = 0; qt < 2; ++qt)
        #pragma unroll
        for (int dh = 0; dh < 2; ++dh) oa[qt][dh] = (f32x4){0.f, 0.f, 0.f, 0.f};
    float lp[2] = {0.f, 0.f};

    for (int ch = 0; ch < 4; ++ch) {
        int ch0 = ch * 256;
        __syncthreads();
        {   // stage 256 keys (lane = key, conflict-free)
            #pragma unroll
            for (int d4 = 0; d4 < 16; d4 += 4) {
                H4 hh;
                #pragma unroll
                for (int i = 0; i < 4; ++i)
                    hh.e[i] = base[(size_t)(16 + d4 + i) * N_ + ch0 + t];
                *(uint2*)&su.m.k_t[t][d4] = hh.u;
            }
        }
        __syncthreads();

        #pragma unroll 4
        for (int kt = 0; kt < 16; ++kt) {
            int key0 = ch0 + kt * 16;
            short8 kf = {0, 0, 0, 0, 0, 0, 0, 0};
            if (quad < 2) kf = *(const short8*)&su.m.k_t[kt * 16 + l16][quad * 8];
            f32x4 zero = {0.f, 0.f, 0.f, 0.f};
            f32x4 sT0 = __builtin_amdgcn_mfma_f32_16x16x32_bf16(kf, qf[0], zero, 0, 0, 0);
            f32x4 sT1 = __builtin_amdgcn_mfma_f32_16x16x32_bf16(kf, qf[1], zero, 0, 0, 0);
            short4b vf0 = *(const short4b*)(base + (size_t)(32 + l16) * N_ + key0 + quad * 4);
            short4b vf1 = *(const short4b*)(base + (size_t)(48 + l16) * N_ + key0 + quad * 4);
            short4b pb0, pb1;
            #pragma unroll
            for (int r = 0; r < 4; ++r) {
                float p = __expf(fminf(sT0[r], 80.f));
                lp[0] += p;
                pb0[r] = f2b(p);
            }
            #pragma unroll
            for (int r = 0; r < 4; ++r) {
                float p = __expf(fminf(sT1[r], 80.f));
                lp[1] += p;
                pb1[r] = f2b(p);
            }
            oa[0][0] = __builtin_amdgcn_mfma_f32_16x16x16bf16_1k(vf0, pb0, oa[0][0], 0, 0, 0);
            oa[0][1] = __builtin_amdgcn_mfma_f32_16x16x16bf16_1k(vf1, pb0, oa[0][1], 0, 0, 0);
            oa[1][0] = __builtin_amdgcn_mfma_f32_16x16x16bf16_1k(vf0, pb1, oa[1][0], 0, 0, 0);
            oa[1][1] = __builtin_amdgcn_mfma_f32_16x16x16bf16_1k(vf1, pb1, oa[1][1], 0, 0, 0);
        }
    }

    // l: sum across quads (lanes differing in bits 4,5), then normalized O -> o_s
    #pragma unroll
    for (int qt = 0; qt < 2; ++qt) {
        float v = lp[qt];
        v += __shfl_xor(v, 16);
        v += __shfl_xor(v, 32);
        float linv = 1.f / fmaxf(v, 1e-30f);
        #pragma unroll
        for (int dh = 0; dh < 2; ++dh)
            #pragma unroll
            for (int r = 0; r < 4; ++r)
                o_s[wv_][dh * 16 + quad * 4 + r][qt * 16 + l16] = f2b(oa[qt][dh][r] * linv);
    }
    __syncthreads();   // main-loop LDS dead; o_s complete

    {   // stage v patch: image rows 4qc-1 .. 4qc+4, 32 d, zeros off-image
        int ybase = qc * 4 - 1;
        int px = t & 31, dg = t >> 5;
        #pragma unroll
        for (int j = 0; j < 6; ++j) {
            int y = ybase + j;
            #pragma unroll
            for (int s = 0; s < 4; ++s) {
                int d = dg + s * 8;
                float v = 0.f;
                if (y >= 0 && y < 32)
                    v = b2f(base[(size_t)(32 + d) * N_ + y * 32 + px]);
                su.v_pe[j * 32 + px][d] = v;
            }
        }
    }
    __syncthreads();

    {   // pe compute + add + transposed bf16 store
        int d = t & 31, pxg = t >> 5;        // 8 groups of 16 pixels
        int c = h * 32 + d;
        float w9[9];
        #pragma unroll
        for (int k = 0; k < 9; ++k) w9[k] = wpe[c * 9 + k];
        float beta = bnpe[c];
        #pragma unroll
        for (int ii = 0; ii < 16; ++ii) {
            int pl = pxg * 16 + ii;          // 0..127 local pixel
            int xx0 = pl & 31;
            float s = beta;
            #pragma unroll
            for (int dy = -1; dy <= 1; ++dy) {
                #pragma unroll
                for (int dx = -1; dx <= 1; ++dx) {
                    int xx = xx0 + dx;
                    if (xx < 0 || xx > 31) continue;
                    s += w9[(dy + 1) * 3 + (dx + 1)] * su.v_pe[pl + 32 + dy * 32 + dx][d];
                }
            }
            float o = b2f(o_s[pl >> 5][d][pl & 31]);
            xattnT[(size_t)(b * N_ + q0g + pl) * DIM_ + c] = f2b(o + s);
        }
    }
}

// ============ Kernel 3: out = BN(proj_w @ xattn) fp32, MFMA ============
__global__ __launch_bounds__(256) void k_proj(
    const u16* __restrict__ xattnT, const u16* __restrict__ wbf,
    const float2* __restrict__ bn, float* __restrict__ out)
{
    int blk = blockIdx.x;
    int nb = blk & 7, ob = (blk >> 3) & 3, b = blk >> 5;
    int t = threadIdx.x;
    int wv_ = t >> 6, lane = t & 63, quad = lane >> 4, l16 = lane & 15;
    int o_base = ob * 64 + (wv_ & 1) * 32;
    int n_base = nb * 128 + (wv_ >> 1) * 64;

    f32x4 acc[2][4];
    #pragma unroll
    for (int ot = 0; ot < 2; ++ot)
        #pragma unroll
        for (int nt = 0; nt < 4; ++nt) acc[ot][nt] = (f32x4){0.f, 0.f, 0.f, 0.f};

    const u16* xb = xattnT + (size_t)b * N_ * DIM_;
    for (int c0 = 0; c0 < DIM_; c0 += 32) {
        short8 af[2];
        #pragma unroll
        for (int ot = 0; ot < 2; ++ot)
            af[ot] = *(const short8*)(wbf + (size_t)(o_base + ot * 16 + l16) * DIM_ + c0 + quad * 8);
        short8 bf[4];
        #pragma unroll
        for (int nt = 0; nt < 4; ++nt)
            bf[nt] = *(const short8*)(xb + (size_t)(n_base + nt * 16 + l16) * DIM_ + c0 + quad * 8);
        #pragma unroll
        for (int ot = 0; ot < 2; ++ot)
            #pragma unroll
            for (int nt = 0; nt < 4; ++nt)
                acc[ot][nt] = __builtin_amdgcn_mfma_f32_16x16x32_bf16(af[ot], bf[nt], acc[ot][nt], 0, 0, 0);
    }
    #pragma unroll
    for (int ot = 0; ot < 2; ++ot)
        #pragma unroll
        for (int r = 0; r < 4; ++r) {
            int o = o_base + ot * 16 + quad * 4 + r;
            float2 ib = bn[o];
            float* dst = out + (size_t)(b * DIM_ + o) * N_ + n_base + l16;
            #pragma unroll
            for (int nt = 0; nt < 4; ++nt)
                dst[nt * 16] = acc[ot][nt][r] * ib.x + ib.y;
        }
}

extern "C" void kernel_launch(void* const* d_in, const int* in_sizes, int n_in,
                              void* d_out, int out_size, void* d_ws, size_t ws_size,
                              hipStream_t stream)
{
    const float* x      = (const float*)d_in[0];
    const float* qkv_w  = (const float*)d_in[1];
    const float* qkv_g  = (const float*)d_in[2];
    const float* qkv_b  = (const float*)d_in[3];
    const float* qkv_m  = (const float*)d_in[4];
    const float* qkv_v  = (const float*)d_in[5];
    const float* pe_w   = (const float*)d_in[6];
    const float* pe_g   = (const float*)d_in[7];
    const float* pe_b   = (const float*)d_in[8];
    const float* pe_m   = (const float*)d_in[9];
    const float* pe_v   = (const float*)d_in[10];
    const float* proj_w = (const float*)d_in[11];
    const float* proj_g = (const float*)d_in[12];
    const float* proj_b = (const float*)d_in[13];
    const float* proj_m = (const float*)d_in[14];
    const float* proj_v = (const float*)d_in[15];
    float* out = (float*)d_out;

    // ws layout
    char* p = (char*)d_ws;
    u16*    qkv    = (u16*)p;    p += (size_t)B_ * HOUT_ * N_ * sizeof(u16);   // 8 MB
    u16*    xT     = (u16*)p;    p += (size_t)B_ * N_ * DIM_ * sizeof(u16);    // 4 MB
    u16*    xattnT = (u16*)p;    p += (size_t)B_ * N_ * DIM_ * sizeof(u16);    // 4 MB
    u16*    wq_bf  = (u16*)p;    p += (size_t)HOUT_ * DIM_ * sizeof(u16);      // 256 KB
    u16*    wp_bf  = (u16*)p;    p += (size_t)DIM_ * DIM_ * sizeof(u16);       // 128 KB
    float2* bnq    = (float2*)p; p += 512 * sizeof(float2);
    float2* bnp    = (float2*)p; p += 256 * sizeof(float2);
    float*  wpe    = (float*)p;  p += 2304 * sizeof(float);
    float*  bnpe   = (float*)p;

    hipLaunchKernelGGL(k_pre, dim3(1024), dim3(256), 0, stream,
                       x, xT, qkv_w, proj_w, pe_w,
                       qkv_g, qkv_b, qkv_m, qkv_v,
                       proj_g, proj_b, proj_m, proj_v,
                       pe_g, pe_b, pe_m, pe_v,
                       wq_bf, wp_bf, bnq, bnp, wpe, bnpe);
    hipLaunchKernelGGL(k_qkv, dim3(512), dim3(256), 0, stream,
                       xT, wq_bf, bnq, qkv);
    hipLaunchKernelGGL(k_attn, dim3(512), dim3(256), 0, stream,
                       qkv, wpe, bnpe, xattnT);
    hipLaunchKernelGGL(k_proj, dim3(256), dim3(256), 0, stream,
                       xattnT, wp_bf, bnp, out);
}

// Round 10
// 152.133 us; speedup vs baseline: 1.2115x; 1.0059x over previous
//
#include <hip/hip_runtime.h>
#include <hip/hip_bf16.h>

#define B_    8
#define DIM_  256
#define NH_   8
#define HD_   32
#define KD_   16
#define HOUT_ 512
#define N_    1024
#define SCALE_ 0.25f
#define EPS_  1e-3f

typedef unsigned short u16;
typedef unsigned int   u32;
typedef __attribute__((ext_vector_type(8)))  short short8;   // 8 bf16 (4 VGPR)
typedef __attribute__((ext_vector_type(4)))  float f32x4;
typedef __attribute__((ext_vector_type(16))) float f32x16;

union H4 { uint2 u; u16 e[4]; };
union FragU { uint4 u; short8 s; };

__device__ __forceinline__ float b2f(u16 u) {
    union { unsigned int i; float f; } c;
    c.i = ((unsigned int)u) << 16;
    return c.f;
}

__device__ __forceinline__ u16 f2b(float f) {
    union { float f; unsigned int i; } c;
    c.f = f;
    unsigned int x = c.i;
    return (u16)((x + 0x7fffu + ((x >> 16) & 1u)) >> 16);  // RNE
}

// ============ Kernel 0: fused prep (weights->bf16, fold BN) + x transpose ============
__global__ __launch_bounds__(256) void k_pre(
    const float* __restrict__ x, u16* __restrict__ xT,
    const float* __restrict__ qw, const float* __restrict__ pw,
    const float* __restrict__ pew,
    const float* __restrict__ qg, const float* __restrict__ qb,
    const float* __restrict__ qm, const float* __restrict__ qv,
    const float* __restrict__ pg, const float* __restrict__ pb,
    const float* __restrict__ pm, const float* __restrict__ pv,
    const float* __restrict__ eg, const float* __restrict__ eb,
    const float* __restrict__ em, const float* __restrict__ ev,
    u16* __restrict__ wq_bf, u16* __restrict__ wp_bf,
    float2* __restrict__ bnq, float2* __restrict__ bnp,
    float* __restrict__ wpe, float* __restrict__ bnpe)
{
    __shared__ float t_s[64][65];
    int blk = blockIdx.x;
    int t = threadIdx.x;
    if (blk >= 512) {
        int i = (blk - 512) * 256 + t;          // 0 .. 131071
        wq_bf[i] = f2b(qw[i]);
        if (i < 65536) wp_bf[i] = f2b(pw[i]);
        if (i < 512) {
            float inv = qg[i] / sqrtf(qv[i] + EPS_);
            bnq[i] = make_float2(inv, qb[i] - qm[i] * inv);
        } else if (i < 768) {
            int o = i - 512;
            float inv = pg[o] / sqrtf(pv[o] + EPS_);
            bnp[o] = make_float2(inv, pb[o] - pm[o] * inv);
        }
        if (i < 2304) {
            int c = i / 9;
            float inv = eg[c] / sqrtf(ev[c] + EPS_);
            wpe[i] = pew[i] * inv;
            if (i % 9 == 0) bnpe[c] = eb[c] - em[c] * inv;
        }
        return;
    }
    int nt = blk & 15, ct = (blk >> 4) & 3, b = blk >> 6;
    int c0 = ct * 64, n0 = nt * 64;
    #pragma unroll
    for (int i = 0; i < 16; ++i) {
        int idx = i * 256 + t;
        int c = idx >> 6, n = idx & 63;
        t_s[n][c] = x[(size_t)(b * DIM_ + c0 + c) * N_ + n0 + n];
    }
    __syncthreads();
    #pragma unroll
    for (int i = 0; i < 16; ++i) {
        int idx = i * 256 + t;
        int n = idx >> 6, c = idx & 63;
        xT[(size_t)(b * N_ + n0 + n) * DIM_ + c0 + c] = f2b(t_s[n][c]);
    }
}

// ============ Kernel 1: qkv = BN(qkv_w @ x) -> bf16 [o][n], MFMA ============
__global__ __launch_bounds__(256) void k_qkv(
    const u16* __restrict__ xT, const u16* __restrict__ wbf,
    const float2* __restrict__ bn, u16* __restrict__ qkv)
{
    int blk = blockIdx.x;
    int nb = blk & 7, ob = (blk >> 3) & 7, b = blk >> 6;
    int t = threadIdx.x;
    int wv_ = t >> 6, lane = t & 63, quad = lane >> 4, l16 = lane & 15;
    int o_base = ob * 64 + (wv_ & 1) * 32;
    int n_base = nb * 128 + (wv_ >> 1) * 64;

    f32x4 acc[2][4];
    #pragma unroll
    for (int ot = 0; ot < 2; ++ot)
        #pragma unroll
        for (int nt = 0; nt < 4; ++nt) acc[ot][nt] = (f32x4){0.f, 0.f, 0.f, 0.f};

    const u16* xb = xT + (size_t)b * N_ * DIM_;
    for (int c0 = 0; c0 < DIM_; c0 += 32) {
        short8 af[2];
        #pragma unroll
        for (int ot = 0; ot < 2; ++ot)
            af[ot] = *(const short8*)(wbf + (size_t)(o_base + ot * 16 + l16) * DIM_ + c0 + quad * 8);
        short8 bf[4];
        #pragma unroll
        for (int nt = 0; nt < 4; ++nt)
            bf[nt] = *(const short8*)(xb + (size_t)(n_base + nt * 16 + l16) * DIM_ + c0 + quad * 8);
        #pragma unroll
        for (int ot = 0; ot < 2; ++ot)
            #pragma unroll
            for (int nt = 0; nt < 4; ++nt)
                acc[ot][nt] = __builtin_amdgcn_mfma_f32_16x16x32_bf16(af[ot], bf[nt], acc[ot][nt], 0, 0, 0);
    }
    #pragma unroll
    for (int ot = 0; ot < 2; ++ot)
        #pragma unroll
        for (int r = 0; r < 4; ++r) {
            int o = o_base + ot * 16 + quad * 4 + r;
            float2 ib = bn[o];
            u16* dst = qkv + (size_t)(b * HOUT_ + o) * N_ + n_base + l16;
            #pragma unroll
            for (int nt = 0; nt < 4; ++nt)
                dst[nt * 16] = f2b(acc[ot][nt][r] * ib.x + ib.y);
        }
}

// ============ Kernel 2: flash attention, 32x32x16 MFMA, register-P, key-split ============
// Per block: 64 q. Waves (kh=wv>>1, qt=wv&1): qt picks 32 q, kh picks 512 keys.
// S^T = mfma_32x32x16(K, Q): C col=q(lane&31), row=key=(reg&3)+8(reg>>2)+4hw.
// One shfl_xor(32) pair-exchange turns those rows into the PV B-operand layout
// (k=hw*8+j). PV: A=V b128 from global (m=d=lane&31), acc = 32d x 32q f32x16.
// Key-split partials (unnormalized O + l) combine via LDS in the fused pe epilogue.
struct MainS { u16 q_t[64][24]; u16 k_t[2][256][24]; };
struct EpiS  { u16 o_acc[2][32][66]; float l_s[2][64]; float v_pe[128][33]; };
union  SmemU { MainS m; EpiS e; };

__global__ __launch_bounds__(256) void k_attn(
    const u16* __restrict__ qkv, const float* __restrict__ wpe,
    const float* __restrict__ bnpe, u16* __restrict__ xattnT)
{
    __shared__ SmemU su;
    int blk = blockIdx.x;
    int qb = blk & 15;
    int h  = (blk >> 4) & 7;
    int b  = blk >> 7;
    int t    = threadIdx.x;
    int wv_  = t >> 6;
    int lane = t & 63;
    int q5   = lane & 31;    // q / key / d index within 32
    int hw   = lane >> 5;    // half-wave
    int kh   = wv_ >> 1;     // key half (0: keys 0-511, 1: 512-1023)
    int qt   = wv_ & 1;      // q tile within block
    const u16* base = qkv + (size_t)(b * HOUT_ + h * 64) * N_;  // q:d, k:16+d, v:32+d
    int q0g = qb * 64;

    {   // stage 64 q transposed + pre-scaled (lane = q, conflict-free)
        int q = t & 63, d4 = (t >> 6) * 4;
        H4 hh;
        #pragma unroll
        for (int i = 0; i < 4; ++i)
            hh.e[i] = f2b(b2f(base[(size_t)(d4 + i) * N_ + q0g + q]) * SCALE_);
        *(uint2*)&su.m.q_t[q][d4] = hh.u;
    }
    __syncthreads();

    short8 qf = *(const short8*)&su.m.q_t[qt * 32 + q5][hw * 8];

    f32x16 oacc = {0.f,0.f,0.f,0.f, 0.f,0.f,0.f,0.f, 0.f,0.f,0.f,0.f, 0.f,0.f,0.f,0.f};
    float l_lane = 0.f;

    for (int ch = 0; ch < 2; ++ch) {
        __syncthreads();
        {   // stage 512 keys (both halves), lane = key, conflict-free
            #pragma unroll
            for (int s2 = 0; s2 < 2; ++s2) {
                int key = s2 * 512 + ch * 256 + t;
                #pragma unroll
                for (int d4 = 0; d4 < 16; d4 += 4) {
                    H4 hh;
                    #pragma unroll
                    for (int i = 0; i < 4; ++i)
                        hh.e[i] = base[(size_t)(16 + d4 + i) * N_ + key];
                    *(uint2*)&su.m.k_t[s2][t][d4] = hh.u;
                }
            }
        }
        __syncthreads();

        #pragma unroll 2
        for (int tile = 0; tile < 8; ++tile) {
            int key0 = kh * 512 + ch * 256 + tile * 32;
            short8 kf = *(const short8*)&su.m.k_t[kh][tile * 32 + q5][hw * 8];
            f32x16 z = {0.f,0.f,0.f,0.f, 0.f,0.f,0.f,0.f, 0.f,0.f,0.f,0.f, 0.f,0.f,0.f,0.f};
            f32x16 sT = __builtin_amdgcn_mfma_f32_32x32x16_bf16(kf, qf, z, 0, 0, 0);
            u32 pk[8];
            #pragma unroll
            for (int j = 0; j < 8; ++j) {
                float p0 = __expf(fminf(sT[2 * j], 80.f));
                float p1 = __expf(fminf(sT[2 * j + 1], 80.f));
                l_lane += p0 + p1;
                pk[j] = (u32)f2b(p0) | ((u32)f2b(p1) << 16);
            }
            #pragma unroll
            for (int s = 0; s < 2; ++s) {
                u32 s0 = hw ? pk[4 * s + 0] : pk[4 * s + 2];
                u32 s1 = hw ? pk[4 * s + 1] : pk[4 * s + 3];
                u32 r0 = __shfl_xor(s0, 32);
                u32 r1 = __shfl_xor(s1, 32);
                FragU pf;
                pf.u.x = hw ? r0 : pk[4 * s + 0];
                pf.u.y = hw ? r1 : pk[4 * s + 1];
                pf.u.z = hw ? pk[4 * s + 2] : r0;
                pf.u.w = hw ? pk[4 * s + 3] : r1;
                const u16* vsrc = base + (size_t)(32 + q5) * N_ + key0 + s * 16 + hw * 8;
                short8 vf = *(const short8*)vsrc;
                oacc = __builtin_amdgcn_mfma_f32_32x32x16_bf16(vf, pf.s, oacc, 0, 0, 0);
            }
        }
    }

    float l_q = l_lane + __shfl_xor(l_lane, 32);
    __syncthreads();   // all k_t/q_t reads done -> e-region reuse safe

    {   // write key-half partials: O (bf16) + l
        int qg = qt * 32 + q5;
        #pragma unroll
        for (int r = 0; r < 16; ++r) {
            int d = (r & 3) + 8 * (r >> 2) + 4 * hw;
            su.e.o_acc[kh][d][qg] = f2b(oacc[r]);
        }
        if (hw == 0) su.e.l_s[kh][qg] = l_q;
    }
    {   // stage v patch: image rows 2qb-1 .. 2qb+2, 32 d, zeros off-image
        int ybase = qb * 2 - 1;
        #pragma unroll
        for (int i = 0; i < 16; ++i) {
            int idx = i * 256 + t;
            int d = idx >> 7, px = idx & 127;
            int y = ybase + (px >> 5);
            float v = 0.f;
            if (y >= 0 && y < 32)
                v = b2f(base[(size_t)(32 + d) * N_ + y * 32 + (px & 31)]);
            su.e.v_pe[px][d] = v;
        }
    }
    __syncthreads();

    {   // combine partials + pe conv + transposed bf16 store
        int d = t & 31, pxg = t >> 5;        // 8 pixel-groups of 8
        int c = h * 32 + d;
        float w9[9];
        #pragma unroll
        for (int k = 0; k < 9; ++k) w9[k] = wpe[c * 9 + k];
        float beta = bnpe[c];
        #pragma unroll
        for (int ii = 0; ii < 8; ++ii) {
            int pl = pxg * 8 + ii;           // 0..63 local pixel
            int xx0 = pl & 31;
            float s = beta;
            #pragma unroll
            for (int dy = -1; dy <= 1; ++dy) {
                #pragma unroll
                for (int dx = -1; dx <= 1; ++dx) {
                    int xx = xx0 + dx;
                    if (xx < 0 || xx > 31) continue;
                    s += w9[(dy + 1) * 3 + (dx + 1)] * su.e.v_pe[pl + 32 + dy * 32 + dx][d];
                }
            }
            float o = b2f(su.e.o_acc[0][d][pl]) + b2f(su.e.o_acc[1][d][pl]);
            float l = su.e.l_s[0][pl] + su.e.l_s[1][pl];
            xattnT[(size_t)(b * N_ + q0g + pl) * DIM_ + c] = f2b(o / fmaxf(l, 1e-30f) + s);
        }
    }
}

// ============ Kernel 3: out = BN(proj_w @ xattn) fp32, MFMA ============
// Block tile 64o x 64n; grid = 8b x 4ob x 16nb = 512 (2 blocks/CU).
__global__ __launch_bounds__(256) void k_proj(
    const u16* __restrict__ xattnT, const u16* __restrict__ wbf,
    const float2* __restrict__ bn, float* __restrict__ out)
{
    int blk = blockIdx.x;
    int nb = blk & 15, ob = (blk >> 4) & 3, b = blk >> 6;
    int t = threadIdx.x;
    int wv_ = t >> 6, lane = t & 63, quad = lane >> 4, l16 = lane & 15;
    int o_base = ob * 64 + (wv_ & 1) * 32;
    int n_base = nb * 64 + (wv_ >> 1) * 32;

    f32x4 acc[2][2];
    #pragma unroll
    for (int ot = 0; ot < 2; ++ot)
        #pragma unroll
        for (int nt = 0; nt < 2; ++nt) acc[ot][nt] = (f32x4){0.f, 0.f, 0.f, 0.f};

    const u16* xb = xattnT + (size_t)b * N_ * DIM_;
    for (int c0 = 0; c0 < DIM_; c0 += 32) {
        short8 af[2];
        #pragma unroll
        for (int ot = 0; ot < 2; ++ot)
            af[ot] = *(const short8*)(wbf + (size_t)(o_base + ot * 16 + l16) * DIM_ + c0 + quad * 8);
        short8 bf[2];
        #pragma unroll
        for (int nt = 0; nt < 2; ++nt)
            bf[nt] = *(const short8*)(xb + (size_t)(n_base + nt * 16 + l16) * DIM_ + c0 + quad * 8);
        #pragma unroll
        for (int ot = 0; ot < 2; ++ot)
            #pragma unroll
            for (int nt = 0; nt < 2; ++nt)
                acc[ot][nt] = __builtin_amdgcn_mfma_f32_16x16x32_bf16(af[ot], bf[nt], acc[ot][nt], 0, 0, 0);
    }
    #pragma unroll
    for (int ot = 0; ot < 2; ++ot)
        #pragma unroll
        for (int r = 0; r < 4; ++r) {
            int o = o_base + ot * 16 + quad * 4 + r;
            float2 ib = bn[o];
            float* dst = out + (size_t)(b * DIM_ + o) * N_ + n_base + l16;
            #pragma unroll
            for (int nt = 0; nt < 2; ++nt)
                dst[nt * 16] = acc[ot][nt][r] * ib.x + ib.y;
        }
}

extern "C" void kernel_launch(void* const* d_in, const int* in_sizes, int n_in,
                              void* d_out, int out_size, void* d_ws, size_t ws_size,
                              hipStream_t stream)
{
    const float* x      = (const float*)d_in[0];
    const float* qkv_w  = (const float*)d_in[1];
    const float* qkv_g  = (const float*)d_in[2];
    const float* qkv_b  = (const float*)d_in[3];
    const float* qkv_m  = (const float*)d_in[4];
    const float* qkv_v  = (const float*)d_in[5];
    const float* pe_w   = (const float*)d_in[6];
    const float* pe_g   = (const float*)d_in[7];
    const float* pe_b   = (const float*)d_in[8];
    const float* pe_m   = (const float*)d_in[9];
    const float* pe_v   = (const float*)d_in[10];
    const float* proj_w = (const float*)d_in[11];
    const float* proj_g = (const float*)d_in[12];
    const float* proj_b = (const float*)d_in[13];
    const float* proj_m = (const float*)d_in[14];
    const float* proj_v = (const float*)d_in[15];
    float* out = (float*)d_out;

    // ws layout
    char* p = (char*)d_ws;
    u16*    qkv    = (u16*)p;    p += (size_t)B_ * HOUT_ * N_ * sizeof(u16);   // 8 MB
    u16*    xT     = (u16*)p;    p += (size_t)B_ * N_ * DIM_ * sizeof(u16);    // 4 MB
    u16*    xattnT = (u16*)p;    p += (size_t)B_ * N_ * DIM_ * sizeof(u16);    // 4 MB
    u16*    wq_bf  = (u16*)p;    p += (size_t)HOUT_ * DIM_ * sizeof(u16);      // 256 KB
    u16*    wp_bf  = (u16*)p;    p += (size_t)DIM_ * DIM_ * sizeof(u16);       // 128 KB
    float2* bnq    = (float2*)p; p += 512 * sizeof(float2);
    float2* bnp    = (float2*)p; p += 256 * sizeof(float2);
    float*  wpe    = (float*)p;  p += 2304 * sizeof(float);
    float*  bnpe   = (float*)p;

    hipLaunchKernelGGL(k_pre, dim3(1024), dim3(256), 0, stream,
                       x, xT, qkv_w, proj_w, pe_w,
                       qkv_g, qkv_b, qkv_m, qkv_v,
                       proj_g, proj_b, proj_m, proj_v,
                       pe_g, pe_b, pe_m, pe_v,
                       wq_bf, wp_bf, bnq, bnp, wpe, bnpe);
    hipLaunchKernelGGL(k_qkv, dim3(512), dim3(256), 0, stream,
                       xT, wq_bf, bnq, qkv);
    hipLaunchKernelGGL(k_attn, dim3(1024), dim3(256), 0, stream,
                       qkv, wpe, bnpe, xattnT);
    hipLaunchKernelGGL(k_proj, dim3(512), dim3(256), 0, stream,
                       xattnT, wp_bf, bnp, out);
}